// Round 19
// baseline (970.597 us; speedup 1.0000x reference)
//
#include <hip/hip_runtime.h>
#include <hip/hip_bf16.h>
#include <cfloat>
#include <cstddef>

#define BB 16
#define NN 2048
#define KNN 30
#define MC 8192   // final-MLP chunk rows

using bf16 = __hip_bfloat16;
typedef short short8 __attribute__((ext_vector_type(8)));
typedef float floatx4 __attribute__((ext_vector_type(4)));

// ---- static device scratch (< 54.4 MB proven-good; loader aborts somewhere below 67.5 MB) ----
constexpr size_t XT_O  = 0;
constexpr size_t NRM_O = XT_O  + (size_t)BB*64*NN;
constexpr size_t A_O   = NRM_O + (size_t)BB*NN;
constexpr size_t U_O   = A_O   + (size_t)BB*NN*64;
constexpr size_t H_O   = U_O   + (size_t)BB*NN*64;      // 6,324,224 floats
constexpr size_t WS_F  = H_O   + (size_t)BB*NN*192;     // 12,615,680 floats = 50.5 MB
// final-MLP aliases over dead XT/nrm/A/U span (short offsets into (short*)g_ws):
constexpr size_t H1C_S = 0;                              // 8192*1024 shorts -> ends fl 4,194,304
constexpr size_t H2C_S = 8388608;                        // 8192*256  shorts -> ends fl 5,242,880
constexpr size_t WB_S  = 11534336;                       // weights base (fl 5,767,168)
constexpr size_t WB1_S = WB_S + 0;                       // 196,608 shorts
constexpr size_t WB2_S = WB_S + 196608;                  // 262,144 shorts
constexpr size_t WB3_S = WB_S + 458752;                  // 32,768 shorts -> ends fl 6,012,928 < H_O ✓

__device__ __attribute__((aligned(16))) float g_ws[WS_F];
__device__ int   g_idx[(size_t)BB*NN*KNN];
__device__ int   g_isbf16;                               // runtime input-dtype flag (measured: fp32 world)

__device__ __forceinline__ float b2f(bf16 x){ return __bfloat162float(x); }
__device__ __forceinline__ float ldi(const void* p, size_t i){
  return g_isbf16 ? b2f(((const bf16*)p)[i]) : ((const float*)p)[i];
}
__device__ __forceinline__ short f2bs(float v){
  bf16 h = __float2bfloat16(v);
  return *reinterpret_cast<short*>(&h);
}
__device__ __forceinline__ float bs2f(short s){
  bf16 h = *reinterpret_cast<bf16*>(&s);
  return __bfloat162float(h);
}
// monotonic u32 key: order-isomorphic to float compare (incl. negatives)
__device__ __forceinline__ unsigned fmono(float x){
  unsigned u = __float_as_uint(x);
  return ((int)u < 0) ? ~u : (u | 0x80000000u);
}

// ---------------------------------------------------------------- diagnostic
__global__ __launch_bounds__(256) void k_diag(bf16* __restrict__ out, int n, float v){
  int t = blockIdx.x*256 + threadIdx.x;
  if(t < n) out[t] = __float2bfloat16(v);
}

// ---------------------------------------------------------------- prep (+inline dtype sniff)
// R36: k_sniff merged in. Each block sniffs the leading 16KB of pos in-registers,
// uses the LOCAL flag for its own loads; block 0 publishes g_isbf16 for later kernels.
__global__ __launch_bounds__(256) void k_prep(const void* __restrict__ pos){
  const int tid = threadIdx.x;
  __shared__ int cnt[256];
  {
    const unsigned* posw = (const unsigned*)pos;
    int c = 0;
    for(int k=0;k<8;k++){
      unsigned w = posw[tid*8+k];
      unsigned code = (w & 0x7F80u) >> 7;
      if(code >= 119u && code <= 129u) c++;
    }
    cnt[tid] = c; __syncthreads();
    for(int s=128;s>0;s>>=1){ if(tid<s) cnt[tid]+=cnt[tid+s]; __syncthreads(); }
  }
  const int isbf = (cnt[0] > 1024) ? 1 : 0;
  if(blockIdx.x == 0 && tid == 0) g_isbf16 = isbf;

  int t = blockIdx.x*256 + tid;                    // grid=128 -> t < 32768 exactly
  int b = t >> 11, i = t & (NN-1);
  float x, y, z;
  if(isbf){
    const bf16* pb = (const bf16*)pos;
    x = b2f(pb[(size_t)t*3+0]); y = b2f(pb[(size_t)t*3+1]); z = b2f(pb[(size_t)t*3+2]);
  } else {
    const float* pf = (const float*)pos;
    x = pf[(size_t)t*3+0]; y = pf[(size_t)t*3+1]; z = pf[(size_t)t*3+2];
  }
  float* Xb = g_ws + XT_O + (size_t)b*64*NN;
  Xb[0*NN+i] = x; Xb[1*NN+i] = y; Xb[2*NN+i] = z;
  g_ws[NRM_O + t] = x*x + y*y + z*z;
}

// ---------------------------------------------------------------- fat kNN + stage_pre
// R35/R29 proven body: knn fp32 (R27: CH=2 dbuf, wave-uniform xi s_loads,
// two-phase 32KB handoff, bisection+ballot select) + stage_pre tail (2048 x 16).
template<int C, bool EXTIN>
__global__ __launch_bounds__(512, 4) void k_knn_pre(const void* __restrict__ Xin,
    int rowStride, int colOff, const void* __restrict__ W0, const void* __restrict__ b0,
    int xOff){
  constexpr int SM_KNN = 4*NN*4;                           // 32 KB keys
  constexpr int SM_PRE = C*64*4*2 + 256 + 16*C*4;          // Wd+Wb+bb+xs
  constexpr int SMB = SM_KNN > SM_PRE ? SM_KNN : SM_PRE;
  __shared__ __attribute__((aligned(16))) char smem[SMB];
  const int tid = threadIdx.x;
  const int wid = tid >> 6, lane = tid & 63;

  if(blockIdx.x >= 4096){
    // ---------------- stage_pre: A = x·(W0a-W0b)+b0, U = x·W0b (16 points/block)
    float* Wd = (float*)smem;
    float* Wb = Wd + C*64;
    float* bb = Wb + C*64;
    float* xs = bb + 64;                                   // [16][C]
    for(int t=tid; t<C*64; t+=512){
      float top = ldi(W0, t), bot = ldi(W0, (size_t)C*64 + t);
      Wd[t] = top - bot; Wb[t] = bot;
    }
    if(tid < 64) bb[tid] = ldi(b0, tid);
    const int pbase = (blockIdx.x - 4096)*16;
    for(int t=tid; t<16*C; t+=512){
      int p = t / C, c = t - p*C;
      float x;
      if(EXTIN) x = ldi(Xin, (size_t)(pbase+p)*rowStride + colOff + c);
      else      x = g_ws[(size_t)xOff + (size_t)(pbase+p)*rowStride + colOff + c];
      xs[p*C + c] = x;
    }
    __syncthreads();
    #pragma unroll
    for(int pp=0; pp<2; pp++){
      const int lp = wid*2 + pp;
      const int point = pbase + lp;
      float a = bb[lane], u = 0.f;
      for(int c=0;c<C;c++){
        float xc = xs[lp*C + c];
        a = fmaf(xc, Wd[c*64 + lane], a);
        u = fmaf(xc, Wb[c*64 + lane], u);
      }
      g_ws[A_O + (size_t)point*64 + lane] = a;
      g_ws[U_O + (size_t)point*64 + lane] = u;
    }
    return;
  }

  // ---------------- kNN (R27 body): two-phase 32KB handoff, bisection select
  unsigned (*dlds)[NN] = (unsigned(*)[NN])smem;
  const int b    = blockIdx.x >> 8;                // 256 blocks per batch
  const int i0   = (blockIdx.x & 255) * 8;         // 8 query rows
  const size_t gi0 = (size_t)b*NN + i0;            // global row base
  const float* Xb  = g_ws + XT_O + (size_t)b*64*NN;
  const float* nrm = g_ws + NRM_O;

  const int j0 = tid*4;                            // this thread's 4 candidate cols
  float4 nj4 = *(const float4*)&nrm[(size_t)b*NN + j0];   // hoisted: latency hides under dot

  float acc[8][4];
  #pragma unroll
  for(int r=0;r<8;r++)
    #pragma unroll
    for(int s=0;s<4;s++) acc[r][s] = 0.f;

  constexpr int CH  = (C == 3) ? 3 : 2;            // chunk size (C=3 -> 3, C=64 -> 2)
  constexpr int NCH = C / CH;                      // chunk count (1 / 32) — exact division
  float4 vb[2][CH];
  #pragma unroll
  for(int cc=0; cc<CH; cc++) vb[0][cc] = *(const float4*)&Xb[(size_t)cc*NN + j0];
  #pragma unroll
  for(int k=0; k<NCH; k++){
    if(k+1 < NCH){                                 // prefetch next chunk (independent loads)
      #pragma unroll
      for(int cc=0; cc<CH; cc++)
        vb[(k+1)&1][cc] = *(const float4*)&Xb[(size_t)((k+1)*CH+cc)*NN + j0];
    }
    #pragma unroll
    for(int cc=0; cc<CH; cc++){
      const int c = k*CH + cc;
      const float4 vj = vb[k&1][cc];
      const float* xr = &Xb[(size_t)c*NN + i0];    // wave-uniform base -> s_load
      #pragma unroll
      for(int r=0;r<8;r++){
        float xc = xr[r];
        acc[r][0] = fmaf(xc, vj.x, acc[r][0]);
        acc[r][1] = fmaf(xc, vj.y, acc[r][1]);
        acc[r][2] = fmaf(xc, vj.z, acc[r][2]);
        acc[r][3] = fmaf(xc, vj.w, acc[r][3]);
      }
    }
  }

  // phase A: rows 0..3 keys -> LDS, waves 0..3 pull their kk to registers
  #pragma unroll
  for(int r=0;r<4;r++){
    float nIr = nrm[gi0 + r];                      // uniform scalar load
    uint4 kv;
    kv.x = fmono(fmaf(-2.f, acc[r][0], nIr + nj4.x));
    kv.y = fmono(fmaf(-2.f, acc[r][1], nIr + nj4.y));
    kv.z = fmono(fmaf(-2.f, acc[r][2], nIr + nj4.z));
    kv.w = fmono(fmaf(-2.f, acc[r][3], nIr + nj4.w));
    *(uint4*)&dlds[r][j0] = kv;
  }
  __syncthreads();
  unsigned kk[32];
  if(wid < 4){
    const unsigned* drow = dlds[wid];
    #pragma unroll
    for(int q=0;q<32;q++) kk[q] = drow[lane + (q<<6)];
  }
  __syncthreads();
  // phase B: rows 4..7 keys -> same LDS, waves 4..7 pull kk
  #pragma unroll
  for(int r=4;r<8;r++){
    float nIr = nrm[gi0 + r];
    uint4 kv;
    kv.x = fmono(fmaf(-2.f, acc[r][0], nIr + nj4.x));
    kv.y = fmono(fmaf(-2.f, acc[r][1], nIr + nj4.y));
    kv.z = fmono(fmaf(-2.f, acc[r][2], nIr + nj4.z));
    kv.w = fmono(fmaf(-2.f, acc[r][3], nIr + nj4.w));
    *(uint4*)&dlds[r-4][j0] = kv;
  }
  __syncthreads();
  if(wid >= 4){
    const unsigned* drow = dlds[wid-4];
    #pragma unroll
    for(int q=0;q<32;q++) kk[q] = drow[lane + (q<<6)];
  }

  // all 8 waves now select concurrently, register-only
  const size_t rowbase = (gi0 + wid)*KNN;

  // bisection: invariant cnt(<lo) < 30 <= cnt(<hi). Keys >= 0x80000000 except rare
  // tiny-negative rounding (self-dist); those are always counted -> invariant still holds.
  unsigned lo = 0x80000000u, hi = 0xFFFFFFFFu;
  unsigned T = 0; bool exact = false;
  while(hi - lo > 1u){
    unsigned mid = lo + ((hi - lo) >> 1);
    int tot = 0;
    #pragma unroll
    for(int q=0;q<32;q++) tot += (int)__popcll(__ballot(kk[q] < mid));
    if(tot == KNN){ T = mid; exact = true; break; }
    if(tot < KNN) lo = mid; else hi = mid;
  }

  int base = 0;
  if(exact){
    // exactly 30 keys strictly below T: compact them out (any order is fine downstream)
    #pragma unroll
    for(int q=0;q<32;q++){
      bool p = kk[q] < T;
      unsigned long long m = __ballot(p);
      if(p){
        int pos = base + __builtin_amdgcn_mbcnt_hi((unsigned)(m>>32),
                        __builtin_amdgcn_mbcnt_lo((unsigned)m, 0u));
        g_idx[rowbase + pos] = lane + (q<<6);
      }
      base += (int)__popcll(m);
    }
  } else {
    // ties at key==lo: strict pass, then ==lo in ascending j (q-major, lane-minor) until 30
    #pragma unroll
    for(int q=0;q<32;q++){
      bool p = kk[q] < lo;
      unsigned long long m = __ballot(p);
      if(p){
        int pos = base + __builtin_amdgcn_mbcnt_hi((unsigned)(m>>32),
                        __builtin_amdgcn_mbcnt_lo((unsigned)m, 0u));
        g_idx[rowbase + pos] = lane + (q<<6);
      }
      base += (int)__popcll(m);
    }
    #pragma unroll
    for(int q=0;q<32;q++){
      bool p = kk[q] == lo;
      unsigned long long m = __ballot(p);
      if(p){
        int pos = base + __builtin_amdgcn_mbcnt_hi((unsigned)(m>>32),
                        __builtin_amdgcn_mbcnt_lo((unsigned)m, 0u));
        if(pos < KNN) g_idx[rowbase + pos] = lane + (q<<6);
      }
      base += (int)__popcll(m);
    }
  }
}

// ---------------------------------------------------------------- edge agg: max_k( relu(a_i+u_j) @ W1 + b1 )
// MFMA dot (R18, verified). R37: U-gather software-pipelined across the 4-point
// loop (+122us total). R38: pipeline deepened one link — jv (g_idx) and a (A)
// for ALL 4 points hoisted to the prologue, so each iteration's prefetch issues
// its 30 U-loads immediately from register-resident indices instead of waiting on
// a ~200cy g_idx load + shfl chain. Same arithmetic/order, bit-identical.
template<bool WRITE_NEXT>
__global__ __launch_bounds__(256) void k_edge_agg(const void* __restrict__ W1,
    const void* __restrict__ b1, int colOff){
  __shared__ short hk_hi[4][32][64] __attribute__((aligned(16)));  // 16 KB
  __shared__ short hk_lo[4][32][64] __attribute__((aligned(16)));  // 16 KB
  const int tid = threadIdx.x;
  const int wid = tid >> 6, lane = tid & 63;
  const int ml = lane & 15, kgl = lane >> 4;
  short8 wh[2][4], wl[2][4];
  #pragma unroll
  for(int kt=0; kt<2; kt++)
    #pragma unroll
    for(int nt=0; nt<4; nt++)
      #pragma unroll
      for(int j=0; j<8; j++){
        float w = ldi(W1, (size_t)(kt*32 + kgl*8 + j)*64 + nt*16 + ml);
        short hi = f2bs(w);
        wh[kt][nt][j] = hi;
        wl[kt][nt][j] = f2bs(w - bs2f(hi));
      }
  const float bias = ldi(b1, lane);
  hk_hi[wid][30][lane] = 0; hk_hi[wid][31][lane] = 0;
  hk_lo[wid][30][lane] = 0; hk_lo[wid][31][lane] = 0;

  const int p0 = blockIdx.x*16 + wid*4;
  // prologue: jv + a for ALL 4 points (coalesced), then gather point 0
  int   jv_all[4];
  float av_all[4];
  #pragma unroll
  for(int pp=0; pp<4; pp++){
    const int point = p0 + pp;
    int jv = 0;
    if(lane < KNN) jv = g_idx[(size_t)point*KNN + lane] & (NN-1);
    jv_all[pp] = jv;
    av_all[pp] = g_ws[A_O + (size_t)point*64 + lane];
  }
  float hval[KNN];
  {
    const int b0_ = p0 >> 11;
    const float* Ub = g_ws + U_O + (size_t)b0_*NN*64;
    #pragma unroll
    for(int kk=0; kk<KNN; kk++){
      int j = __shfl(jv_all[0], kk, 64);
      hval[kk] = Ub[(size_t)j*64 + lane];
    }
  }

  for(int pp=0; pp<4; pp++){
    const int point = p0 + pp;
    const int b = point >> 11, i = point & (NN-1);
    const float a = av_all[pp];
    // convert + store current point's h into LDS (reads hval; frees it for prefetch)
    #pragma unroll
    for(int kk=0; kk<KNN; kk++){
      float h = fmaxf(a + hval[kk], 0.f);
      short hi = f2bs(h);
      hk_hi[wid][kk][lane] = hi;
      hk_lo[wid][kk][lane] = f2bs(h - bs2f(hi));
    }
    // prefetch next point's gather into hval (indices already in regs; overlaps MFMA)
    if(pp < 3){
      const int nb = (point + 1) >> 11;
      const float* Ub = g_ws + U_O + (size_t)nb*NN*64;
      int njv = jv_all[pp+1];
      #pragma unroll
      for(int kk=0; kk<KNN; kk++){
        int j = __shfl(njv, kk, 64);
        hval[kk] = Ub[(size_t)j*64 + lane];
      }
    }
    floatx4 acc[2][4];
    #pragma unroll
    for(int t=0;t<2;t++)
      #pragma unroll
      for(int nt=0;nt<4;nt++) acc[t][nt] = (floatx4){0.f,0.f,0.f,0.f};
    #pragma unroll
    for(int t=0;t<2;t++){
      #pragma unroll
      for(int kt=0;kt<2;kt++){
        short8 ah = *(const short8*)&hk_hi[wid][t*16+ml][kt*32 + kgl*8];
        short8 al = *(const short8*)&hk_lo[wid][t*16+ml][kt*32 + kgl*8];
        #pragma unroll
        for(int nt=0;nt<4;nt++){
          acc[t][nt] = __builtin_amdgcn_mfma_f32_16x16x32_bf16(ah, wh[kt][nt], acc[t][nt], 0,0,0);
          acc[t][nt] = __builtin_amdgcn_mfma_f32_16x16x32_bf16(ah, wl[kt][nt], acc[t][nt], 0,0,0);
          acc[t][nt] = __builtin_amdgcn_mfma_f32_16x16x32_bf16(al, wh[kt][nt], acc[t][nt], 0,0,0);
        }
      }
    }
    float cmax[4];
    #pragma unroll
    for(int nt=0;nt<4;nt++){
      float mx = -FLT_MAX;
      #pragma unroll
      for(int t=0;t<2;t++)
        #pragma unroll
        for(int reg=0;reg<4;reg++){
          int m = t*16 + kgl*4 + reg;
          if(m < KNN) mx = fmaxf(mx, acc[t][nt][reg]);
        }
      mx = fmaxf(mx, __shfl_xor(mx, 16, 64));
      mx = fmaxf(mx, __shfl_xor(mx, 32, 64));
      cmax[nt] = mx;
    }
    float r01 = (lane & 16) ? cmax[1] : cmax[0];
    float r23 = (lane & 16) ? cmax[3] : cmax[2];
    float accf = ((lane & 32) ? r23 : r01) + bias;
    g_ws[H_O + (size_t)point*192 + colOff + lane] = accf;
    if(WRITE_NEXT){
      g_ws[XT_O + ((size_t)b*64 + lane)*NN + i] = accf; // transposed copy for next kNN
      float sq = accf*accf;
      #pragma unroll
      for(int off=32; off>0; off>>=1) sq += __shfl_xor(sq, off, 64);
      if(lane == 0) g_ws[NRM_O + point] = sq;
    }
  }
}

// ---------------------------------------------------------------- weight preconvert (all 3): fp32 [K][N] -> fragment-major bf16
__global__ __launch_bounds__(256) void k_wconv3(const void* __restrict__ W0,
    const void* __restrict__ W1, const void* __restrict__ W2){
  int t = blockIdx.x*256 + threadIdx.x;            // grid=1920 -> t < 491520 exactly
  const void* W; int dstOff, rel, lg;
  if(t < 196608)      { W = W0; dstOff = (int)WB1_S; rel = t;          lg = 10; }
  else if(t < 458752) { W = W1; dstOff = (int)WB2_S; rel = t - 196608; lg = 8;  }
  else                { W = W2; dstOff = (int)WB3_S; rel = t - 458752; lg = 7;  }
  int k = rel >> lg, n = rel & ((1<<lg)-1);
  short* dst = (short*)g_ws + dstOff;
  dst[((size_t)((k>>3) << lg) + ((size_t)n))*8 + (k&7)] = f2bs(ldi(W, rel));
}

// ---------------------------------------------------------------- MFMA GEMM: Out = act(A @ W + bias)
// Block 256 = 2x2 waves, tile 128x128, wave 64x64, K-step 32, mfma_f32_16x16x32_bf16.
template<bool ABF16, bool RELU, bool OUTBF16>
__global__ __launch_bounds__(256) void k_mgemm(int aOff, int wOffS, const void* __restrict__ bias,
    int outOff, int Kd, int Nn){
  __shared__ short As[4*128*8] __attribute__((aligned(16)));   // [kg][m][j] 8 KB
  __shared__ short Bs[4*128*8] __attribute__((aligned(16)));   // [kg][n][j] 8 KB
  const int tid = threadIdx.x;
  const int lane = tid & 63, wid = tid >> 6;
  const int waveM = wid >> 1, waveN = wid & 1;
  const int m0 = blockIdx.x * 128, n0 = blockIdx.y * 128;
  const int sm = tid >> 1, skg0 = (tid & 1) * 2;     // A-stage: row sm, k-groups skg0,skg0+1
  const int bn = tid & 127, bkg = tid >> 7;          // B-stage: n, k-groups bkg, bkg+2
  const short* Wb = (const short*)g_ws + wOffS;
  floatx4 acc[4][4];
  #pragma unroll
  for(int a=0;a<4;a++)
    #pragma unroll
    for(int bq=0;bq<4;bq++) acc[a][bq] = (floatx4){0.f,0.f,0.f,0.f};

  for(int k0 = 0; k0 < Kd; k0 += 32){
    if(ABF16){
      const short* Ab = (const short*)g_ws + aOff + (size_t)(m0+sm)*Kd + k0 + skg0*8;
      short8 v0 = *(const short8*)Ab;
      short8 v1 = *(const short8*)(Ab+8);
      *(short8*)&As[((skg0  )*128 + sm)*8] = v0;
      *(short8*)&As[((skg0+1)*128 + sm)*8] = v1;
    } else {
      const float* Af = g_ws + aOff + (size_t)(m0+sm)*Kd + k0 + skg0*8;
      float4 f0 = *(const float4*)(Af+0);
      float4 f1 = *(const float4*)(Af+4);
      float4 f2 = *(const float4*)(Af+8);
      float4 f3 = *(const float4*)(Af+12);
      short8 s0, s1;
      s0[0]=f2bs(f0.x); s0[1]=f2bs(f0.y); s0[2]=f2bs(f0.z); s0[3]=f2bs(f0.w);
      s0[4]=f2bs(f1.x); s0[5]=f2bs(f1.y); s0[6]=f2bs(f1.z); s0[7]=f2bs(f1.w);
      s1[0]=f2bs(f2.x); s1[1]=f2bs(f2.y); s1[2]=f2bs(f2.z); s1[3]=f2bs(f2.w);
      s1[4]=f2bs(f3.x); s1[5]=f2bs(f3.y); s1[6]=f2bs(f3.z); s1[7]=f2bs(f3.w);
      *(short8*)&As[((skg0  )*128 + sm)*8] = s0;
      *(short8*)&As[((skg0+1)*128 + sm)*8] = s1;
    }
    #pragma unroll
    for(int i=0;i<2;i++){
      int kg = bkg + i*2;
      const short* src = Wb + ((size_t)((k0>>3) + kg)*Nn + n0 + bn)*8;
      *(short8*)&Bs[(kg*128 + bn)*8] = *(const short8*)src;
    }
    __syncthreads();
    const int kgl = lane >> 4, ml = lane & 15;
    short8 af[4], bf[4];
    #pragma unroll
    for(int t=0;t<4;t++){
      af[t] = *(const short8*)&As[(kgl*128 + waveM*64 + t*16 + ml)*8];
      bf[t] = *(const short8*)&Bs[(kgl*128 + waveN*64 + t*16 + ml)*8];
    }
    #pragma unroll
    for(int tm=0;tm<4;tm++)
      #pragma unroll
      for(int tn=0;tn<4;tn++)
        acc[tm][tn] = __builtin_amdgcn_mfma_f32_16x16x32_bf16(af[tm], bf[tn], acc[tm][tn], 0, 0, 0);
    __syncthreads();
  }
  // epilogue: D col=lane&15, row=(lane>>4)*4+reg  [m89]
  const int kgl = lane >> 4, ml = lane & 15;
  #pragma unroll
  for(int tn=0;tn<4;tn++){
    int n = n0 + waveN*64 + tn*16 + ml;
    float bv = ldi(bias, n);
    #pragma unroll
    for(int tm=0;tm<4;tm++){
      #pragma unroll
      for(int reg=0;reg<4;reg++){
        int m = m0 + waveM*64 + tm*16 + kgl*4 + reg;
        float v = acc[tm][tn][reg] + bv;
        if(RELU) v = fmaxf(v, 0.f);
        if(OUTBF16) ((short*)g_ws)[(size_t)outOff + (size_t)m*Nn + n] = f2bs(v);
        else        g_ws[(size_t)outOff + (size_t)m*Nn + n] = v;
      }
    }
  }
}

// ---------------------------------------------------------------- fused w2-GEMM (256->128, no relu) + final 128->3
// Tile m=128 x n=128(full). h3 kept fp32 in LDS (one less bf16 rounding than old k_final path).
__global__ __launch_bounds__(256) void k_mgemm_fin(int aOff, int wOffS,
    const void* __restrict__ bias, const void* __restrict__ FW, const void* __restrict__ FB,
    void* __restrict__ out, int outPointBase){
  __shared__ short As[4*128*8] __attribute__((aligned(16)));   // 8 KB
  __shared__ short Bs[4*128*8] __attribute__((aligned(16)));   // 8 KB
  __shared__ float h3[128][129];                               // 66 KB (pad: conflict-free col reads)
  __shared__ float wf[384];
  __shared__ float fb3[3];
  const int Kd = 256, Nn = 128;
  const int tid = threadIdx.x;
  const int lane = tid & 63, wid = tid >> 6;
  const int waveM = wid >> 1, waveN = wid & 1;
  const int m0 = blockIdx.x * 128;
  const int sm = tid >> 1, skg0 = (tid & 1) * 2;
  const int bn = tid & 127, bkg = tid >> 7;
  const short* Wb = (const short*)g_ws + wOffS;
  for(int t=tid; t<384; t+=256) wf[t] = ldi(FW, t);
  if(tid < 3) fb3[tid] = ldi(FB, tid);
  floatx4 acc[4][4];
  #pragma unroll
  for(int a=0;a<4;a++)
    #pragma unroll
    for(int bq=0;bq<4;bq++) acc[a][bq] = (floatx4){0.f,0.f,0.f,0.f};

  for(int k0 = 0; k0 < Kd; k0 += 32){
    const short* Ab = (const short*)g_ws + aOff + (size_t)(m0+sm)*Kd + k0 + skg0*8;
    short8 v0 = *(const short8*)Ab;
    short8 v1 = *(const short8*)(Ab+8);
    *(short8*)&As[((skg0  )*128 + sm)*8] = v0;
    *(short8*)&As[((skg0+1)*128 + sm)*8] = v1;
    #pragma unroll
    for(int i=0;i<2;i++){
      int kg = bkg + i*2;
      const short* src = Wb + ((size_t)((k0>>3) + kg)*Nn + bn)*8;
      *(short8*)&Bs[(kg*128 + bn)*8] = *(const short8*)src;
    }
    __syncthreads();
    const int kgl = lane >> 4, ml = lane & 15;
    short8 af[4], bf[4];
    #pragma unroll
    for(int t=0;t<4;t++){
      af[t] = *(const short8*)&As[(kgl*128 + waveM*64 + t*16 + ml)*8];
      bf[t] = *(const short8*)&Bs[(kgl*128 + waveN*64 + t*16 + ml)*8];
    }
    #pragma unroll
    for(int tm=0;tm<4;tm++)
      #pragma unroll
      for(int tn=0;tn<4;tn++)
        acc[tm][tn] = __builtin_amdgcn_mfma_f32_16x16x32_bf16(af[tm], bf[tn], acc[tm][tn], 0, 0, 0);
    __syncthreads();
  }
  const int kgl = lane >> 4, ml = lane & 15;
  #pragma unroll
  for(int tn=0;tn<4;tn++){
    int n = waveN*64 + tn*16 + ml;
    float bv = ldi(bias, n);
    #pragma unroll
    for(int tm=0;tm<4;tm++){
      #pragma unroll
      for(int reg=0;reg<4;reg++){
        int m = waveM*64 + tm*16 + kgl*4 + reg;
        h3[m][n] = acc[tm][tn][reg] + bv;
      }
    }
  }
  __syncthreads();
  if(tid < 128){
    float a0 = fb3[0], a1 = fb3[1], a2 = fb3[2];
    #pragma unroll 8
    for(int c=0;c<128;c++){
      float x = h3[tid][c];
      a0 = fmaf(x, wf[c*3+0], a0);
      a1 = fmaf(x, wf[c*3+1], a1);
      a2 = fmaf(x, wf[c*3+2], a2);
    }
    size_t o = (size_t)(outPointBase + blockIdx.x*128 + tid)*3;
    if(g_isbf16){
      bf16* ob = (bf16*)out;
      ob[o+0] = __float2bfloat16(a0); ob[o+1] = __float2bfloat16(a1); ob[o+2] = __float2bfloat16(a2);
    } else {
      float* of = (float*)out;
      of[o+0] = a0; of[o+1] = a1; of[o+2] = a2;
    }
  }
}

extern "C" void kernel_launch(void* const* d_in, const int* in_sizes, int n_in,
                              void* d_out, int out_size, void* d_ws, size_t ws_size,
                              hipStream_t stream){
  (void)d_ws; (void)ws_size;
  static const int EXP[21] = {98304, 384,64, 4096,64, 8192,64, 4096,64, 8192,64, 4096,64,
                              196608,1024, 262144,256, 32768,128, 384,3};
  const void* in[21];
  int posmatch = 0;
  bool run = false;
  if(n_in == 21){
    for(int e=0; e<21; e++) posmatch += (in_sizes[e] == EXP[e]) ? 1 : 0;
    if(posmatch == 21){
      for(int e=0; e<21; e++) in[e] = d_in[e];
      run = true;
    } else {
      bool used[21] = {false}; const void* m[21]; bool ok = true;
      for(int e=0; e<21 && ok; e++){
        int hit = -1;
        for(int i2=0; i2<21; i2++)
          if(!used[i2] && in_sizes[i2] == EXP[e]){ hit = i2; break; }
        if(hit < 0) ok = false;
        else { used[hit] = true; m[e] = d_in[hit]; }
      }
      if(ok){ for(int e=0; e<21; e++) in[e] = m[e]; run = true; }
    }
  }
  if(!run){
    float V = 1000.f*(float)n_in + 10.f*(float)posmatch;
    k_diag<<<(out_size+255)/256, 256, 0, stream>>>((bf16*)d_out, out_size, V);
    return;
  }
  const void* pos  = in[0];
  const void* c1w0 = in[1];  const void* c1b0 = in[2];
  const void* c1w1 = in[3];  const void* c1b1 = in[4];
  const void* c2w0 = in[5];  const void* c2b0 = in[6];
  const void* c2w1 = in[7];  const void* c2b1 = in[8];
  const void* c3w0 = in[9];  const void* c3b0 = in[10];
  const void* c3w1 = in[11]; const void* c3b1 = in[12];
  const void* mw0  = in[13]; const void* mb0  = in[14];
  const void* mw1  = in[15]; const void* mb1  = in[16];
  const void* mw2  = in[17]; const void* mb2  = in[18];
  const void* fw   = in[19]; const void* fb   = in[20];

  dim3 b256(256);
  dim3 b512(512);
  k_prep<<<128, b256, 0, stream>>>(pos);           // R36: sniff folded in

  // stage 1 (C=3): fat = knn (blocks 0..4095) + stage_pre (blocks 4096..6143)
  k_knn_pre<3,true><<<6144, b512, 0, stream>>>(pos, 3, 0, c1w0, c1b0, 0);
  k_edge_agg<true><<<2048, b256, 0, stream>>>(c1w1, c1b1, 0);

  // stage 2 (C=64): x1 transposed in XT (stage-1 edge_agg); xi from H cols 0..63
  k_knn_pre<64,false><<<6144, b512, 0, stream>>>(nullptr, 192, 0, c2w0, c2b0, (int)H_O);
  k_edge_agg<true><<<2048, b256, 0, stream>>>(c2w1, c2b1, 64);

  // stage 3 (C=64): x2 transposed in XT; xi from H cols 64..127
  k_knn_pre<64,false><<<6144, b512, 0, stream>>>(nullptr, 192, 64, c3w0, c3b0, (int)H_O);
  k_edge_agg<false><<<2048, b256, 0, stream>>>(c3w1, c3b1, 128);

  // weight preconvert AFTER stage 3 (targets alias U-region, dead from here on)
  k_wconv3<<<1920, b256, 0, stream>>>(mw0, mw1, mw2);

  // final MLP: MFMA bf16, chunked M=8192; w2-GEMM + 128->3 fused (no H3 round-trip)
  for(int ch=0; ch<4; ch++){
    int ainOff = (int)(H_O + (size_t)ch*MC*192);
    k_mgemm<false,true ,true ><<<dim3(64,8), b256, 0, stream>>>(ainOff,     (int)WB1_S, mb0, (int)H1C_S, 192, 1024);
    k_mgemm<true ,true ,true ><<<dim3(64,2), b256, 0, stream>>>((int)H1C_S, (int)WB2_S, mb1, (int)H2C_S, 1024, 256);
    k_mgemm_fin<<<64, b256, 0, stream>>>((int)H2C_S, (int)WB3_S, mb2, fw, fb, d_out, ch*MC);
  }
}

// Round 20
// 908.181 us; speedup vs baseline: 1.0687x; 1.0687x over previous
//
#include <hip/hip_runtime.h>
#include <hip/hip_bf16.h>
#include <cfloat>
#include <cstddef>

#define BB 16
#define NN 2048
#define KNN 30
#define MC 8192   // final-MLP chunk rows

using bf16 = __hip_bfloat16;
typedef short short8 __attribute__((ext_vector_type(8)));
typedef float floatx4 __attribute__((ext_vector_type(4)));

// ---- static device scratch (< 54.4 MB proven-good; loader aborts somewhere below 67.5 MB) ----
constexpr size_t XT_O  = 0;
constexpr size_t NRM_O = XT_O  + (size_t)BB*64*NN;
constexpr size_t A_O   = NRM_O + (size_t)BB*NN;
constexpr size_t U_O   = A_O   + (size_t)BB*NN*64;
constexpr size_t H_O   = U_O   + (size_t)BB*NN*64;      // 6,324,224 floats
constexpr size_t WS_F  = H_O   + (size_t)BB*NN*192;     // 12,615,680 floats = 50.5 MB
// final-MLP aliases over dead XT/nrm/A/U span (short offsets into (short*)g_ws):
constexpr size_t H1C_S = 0;                              // 8192*1024 shorts -> ends fl 4,194,304
constexpr size_t H2C_S = 8388608;                        // 8192*256  shorts -> ends fl 5,242,880
constexpr size_t WB_S  = 11534336;                       // weights base (fl 5,767,168)
constexpr size_t WB1_S = WB_S + 0;                       // 196,608 shorts
constexpr size_t WB2_S = WB_S + 196608;                  // 262,144 shorts
constexpr size_t WB3_S = WB_S + 458752;                  // 32,768 shorts -> ends fl 6,012,928 < H_O ✓

__device__ __attribute__((aligned(16))) float g_ws[WS_F];
__device__ int   g_idx[(size_t)BB*NN*KNN];
__device__ int   g_isbf16;                               // runtime input-dtype flag (measured: fp32 world)

__device__ __forceinline__ float b2f(bf16 x){ return __bfloat162float(x); }
__device__ __forceinline__ float ldi(const void* p, size_t i){
  return g_isbf16 ? b2f(((const bf16*)p)[i]) : ((const float*)p)[i];
}
__device__ __forceinline__ short f2bs(float v){
  bf16 h = __float2bfloat16(v);
  return *reinterpret_cast<short*>(&h);
}
__device__ __forceinline__ float bs2f(short s){
  bf16 h = *reinterpret_cast<bf16*>(&s);
  return __bfloat162float(h);
}
// monotonic u32 key: order-isomorphic to float compare (incl. negatives)
__device__ __forceinline__ unsigned fmono(float x){
  unsigned u = __float_as_uint(x);
  return ((int)u < 0) ? ~u : (u | 0x80000000u);
}

// ---------------------------------------------------------------- diagnostic
__global__ __launch_bounds__(256) void k_diag(bf16* __restrict__ out, int n, float v){
  int t = blockIdx.x*256 + threadIdx.x;
  if(t < n) out[t] = __float2bfloat16(v);
}

// ---------------------------------------------------------------- prep (+inline dtype sniff)
// R36: k_sniff merged in. Each block sniffs the leading 16KB of pos in-registers,
// uses the LOCAL flag for its own loads; block 0 publishes g_isbf16 for later kernels.
__global__ __launch_bounds__(256) void k_prep(const void* __restrict__ pos){
  const int tid = threadIdx.x;
  __shared__ int cnt[256];
  {
    const unsigned* posw = (const unsigned*)pos;
    int c = 0;
    for(int k=0;k<8;k++){
      unsigned w = posw[tid*8+k];
      unsigned code = (w & 0x7F80u) >> 7;
      if(code >= 119u && code <= 129u) c++;
    }
    cnt[tid] = c; __syncthreads();
    for(int s=128;s>0;s>>=1){ if(tid<s) cnt[tid]+=cnt[tid+s]; __syncthreads(); }
  }
  const int isbf = (cnt[0] > 1024) ? 1 : 0;
  if(blockIdx.x == 0 && tid == 0) g_isbf16 = isbf;

  int t = blockIdx.x*256 + tid;                    // grid=128 -> t < 32768 exactly
  int b = t >> 11, i = t & (NN-1);
  float x, y, z;
  if(isbf){
    const bf16* pb = (const bf16*)pos;
    x = b2f(pb[(size_t)t*3+0]); y = b2f(pb[(size_t)t*3+1]); z = b2f(pb[(size_t)t*3+2]);
  } else {
    const float* pf = (const float*)pos;
    x = pf[(size_t)t*3+0]; y = pf[(size_t)t*3+1]; z = pf[(size_t)t*3+2];
  }
  float* Xb = g_ws + XT_O + (size_t)b*64*NN;
  Xb[0*NN+i] = x; Xb[1*NN+i] = y; Xb[2*NN+i] = z;
  g_ws[NRM_O + t] = x*x + y*y + z*z;
}

// ---------------------------------------------------------------- fat kNN + stage_pre
// R35/R29 proven body: knn fp32 (R27: CH=2 dbuf, wave-uniform xi s_loads,
// two-phase 32KB handoff, bisection+ballot select) + stage_pre tail (2048 x 16).
template<int C, bool EXTIN>
__global__ __launch_bounds__(512, 4) void k_knn_pre(const void* __restrict__ Xin,
    int rowStride, int colOff, const void* __restrict__ W0, const void* __restrict__ b0,
    int xOff){
  constexpr int SM_KNN = 4*NN*4;                           // 32 KB keys
  constexpr int SM_PRE = C*64*4*2 + 256 + 16*C*4;          // Wd+Wb+bb+xs
  constexpr int SMB = SM_KNN > SM_PRE ? SM_KNN : SM_PRE;
  __shared__ __attribute__((aligned(16))) char smem[SMB];
  const int tid = threadIdx.x;
  const int wid = tid >> 6, lane = tid & 63;

  if(blockIdx.x >= 4096){
    // ---------------- stage_pre: A = x·(W0a-W0b)+b0, U = x·W0b (16 points/block)
    float* Wd = (float*)smem;
    float* Wb = Wd + C*64;
    float* bb = Wb + C*64;
    float* xs = bb + 64;                                   // [16][C]
    for(int t=tid; t<C*64; t+=512){
      float top = ldi(W0, t), bot = ldi(W0, (size_t)C*64 + t);
      Wd[t] = top - bot; Wb[t] = bot;
    }
    if(tid < 64) bb[tid] = ldi(b0, tid);
    const int pbase = (blockIdx.x - 4096)*16;
    for(int t=tid; t<16*C; t+=512){
      int p = t / C, c = t - p*C;
      float x;
      if(EXTIN) x = ldi(Xin, (size_t)(pbase+p)*rowStride + colOff + c);
      else      x = g_ws[(size_t)xOff + (size_t)(pbase+p)*rowStride + colOff + c];
      xs[p*C + c] = x;
    }
    __syncthreads();
    #pragma unroll
    for(int pp=0; pp<2; pp++){
      const int lp = wid*2 + pp;
      const int point = pbase + lp;
      float a = bb[lane], u = 0.f;
      for(int c=0;c<C;c++){
        float xc = xs[lp*C + c];
        a = fmaf(xc, Wd[c*64 + lane], a);
        u = fmaf(xc, Wb[c*64 + lane], u);
      }
      g_ws[A_O + (size_t)point*64 + lane] = a;
      g_ws[U_O + (size_t)point*64 + lane] = u;
    }
    return;
  }

  // ---------------- kNN (R27 body): two-phase 32KB handoff, bisection select
  unsigned (*dlds)[NN] = (unsigned(*)[NN])smem;
  const int b    = blockIdx.x >> 8;                // 256 blocks per batch
  const int i0   = (blockIdx.x & 255) * 8;         // 8 query rows
  const size_t gi0 = (size_t)b*NN + i0;            // global row base
  const float* Xb  = g_ws + XT_O + (size_t)b*64*NN;
  const float* nrm = g_ws + NRM_O;

  const int j0 = tid*4;                            // this thread's 4 candidate cols
  float4 nj4 = *(const float4*)&nrm[(size_t)b*NN + j0];   // hoisted: latency hides under dot

  float acc[8][4];
  #pragma unroll
  for(int r=0;r<8;r++)
    #pragma unroll
    for(int s=0;s<4;s++) acc[r][s] = 0.f;

  constexpr int CH  = (C == 3) ? 3 : 2;            // chunk size (C=3 -> 3, C=64 -> 2)
  constexpr int NCH = C / CH;                      // chunk count (1 / 32) — exact division
  float4 vb[2][CH];
  #pragma unroll
  for(int cc=0; cc<CH; cc++) vb[0][cc] = *(const float4*)&Xb[(size_t)cc*NN + j0];
  #pragma unroll
  for(int k=0; k<NCH; k++){
    if(k+1 < NCH){                                 // prefetch next chunk (independent loads)
      #pragma unroll
      for(int cc=0; cc<CH; cc++)
        vb[(k+1)&1][cc] = *(const float4*)&Xb[(size_t)((k+1)*CH+cc)*NN + j0];
    }
    #pragma unroll
    for(int cc=0; cc<CH; cc++){
      const int c = k*CH + cc;
      const float4 vj = vb[k&1][cc];
      const float* xr = &Xb[(size_t)c*NN + i0];    // wave-uniform base -> s_load
      #pragma unroll
      for(int r=0;r<8;r++){
        float xc = xr[r];
        acc[r][0] = fmaf(xc, vj.x, acc[r][0]);
        acc[r][1] = fmaf(xc, vj.y, acc[r][1]);
        acc[r][2] = fmaf(xc, vj.z, acc[r][2]);
        acc[r][3] = fmaf(xc, vj.w, acc[r][3]);
      }
    }
  }

  // phase A: rows 0..3 keys -> LDS, waves 0..3 pull their kk to registers
  #pragma unroll
  for(int r=0;r<4;r++){
    float nIr = nrm[gi0 + r];                      // uniform scalar load
    uint4 kv;
    kv.x = fmono(fmaf(-2.f, acc[r][0], nIr + nj4.x));
    kv.y = fmono(fmaf(-2.f, acc[r][1], nIr + nj4.y));
    kv.z = fmono(fmaf(-2.f, acc[r][2], nIr + nj4.z));
    kv.w = fmono(fmaf(-2.f, acc[r][3], nIr + nj4.w));
    *(uint4*)&dlds[r][j0] = kv;
  }
  __syncthreads();
  unsigned kk[32];
  if(wid < 4){
    const unsigned* drow = dlds[wid];
    #pragma unroll
    for(int q=0;q<32;q++) kk[q] = drow[lane + (q<<6)];
  }
  __syncthreads();
  // phase B: rows 4..7 keys -> same LDS, waves 4..7 pull kk
  #pragma unroll
  for(int r=4;r<8;r++){
    float nIr = nrm[gi0 + r];
    uint4 kv;
    kv.x = fmono(fmaf(-2.f, acc[r][0], nIr + nj4.x));
    kv.y = fmono(fmaf(-2.f, acc[r][1], nIr + nj4.y));
    kv.z = fmono(fmaf(-2.f, acc[r][2], nIr + nj4.z));
    kv.w = fmono(fmaf(-2.f, acc[r][3], nIr + nj4.w));
    *(uint4*)&dlds[r-4][j0] = kv;
  }
  __syncthreads();
  if(wid >= 4){
    const unsigned* drow = dlds[wid-4];
    #pragma unroll
    for(int q=0;q<32;q++) kk[q] = drow[lane + (q<<6)];
  }

  // all 8 waves now select concurrently, register-only
  const size_t rowbase = (gi0 + wid)*KNN;

  // bisection: invariant cnt(<lo) < 30 <= cnt(<hi). Keys >= 0x80000000 except rare
  // tiny-negative rounding (self-dist); those are always counted -> invariant still holds.
  unsigned lo = 0x80000000u, hi = 0xFFFFFFFFu;
  unsigned T = 0; bool exact = false;
  while(hi - lo > 1u){
    unsigned mid = lo + ((hi - lo) >> 1);
    int tot = 0;
    #pragma unroll
    for(int q=0;q<32;q++) tot += (int)__popcll(__ballot(kk[q] < mid));
    if(tot == KNN){ T = mid; exact = true; break; }
    if(tot < KNN) lo = mid; else hi = mid;
  }

  int base = 0;
  if(exact){
    // exactly 30 keys strictly below T: compact them out (any order is fine downstream)
    #pragma unroll
    for(int q=0;q<32;q++){
      bool p = kk[q] < T;
      unsigned long long m = __ballot(p);
      if(p){
        int pos = base + __builtin_amdgcn_mbcnt_hi((unsigned)(m>>32),
                        __builtin_amdgcn_mbcnt_lo((unsigned)m, 0u));
        g_idx[rowbase + pos] = lane + (q<<6);
      }
      base += (int)__popcll(m);
    }
  } else {
    // ties at key==lo: strict pass, then ==lo in ascending j (q-major, lane-minor) until 30
    #pragma unroll
    for(int q=0;q<32;q++){
      bool p = kk[q] < lo;
      unsigned long long m = __ballot(p);
      if(p){
        int pos = base + __builtin_amdgcn_mbcnt_hi((unsigned)(m>>32),
                        __builtin_amdgcn_mbcnt_lo((unsigned)m, 0u));
        g_idx[rowbase + pos] = lane + (q<<6);
      }
      base += (int)__popcll(m);
    }
    #pragma unroll
    for(int q=0;q<32;q++){
      bool p = kk[q] == lo;
      unsigned long long m = __ballot(p);
      if(p){
        int pos = base + __builtin_amdgcn_mbcnt_hi((unsigned)(m>>32),
                        __builtin_amdgcn_mbcnt_lo((unsigned)m, 0u));
        if(pos < KNN) g_idx[rowbase + pos] = lane + (q<<6);
      }
      base += (int)__popcll(m);
    }
  }
}

// ---------------------------------------------------------------- edge agg: max_k( relu(a_i+u_j) @ W1 + b1 )
// MFMA dot (R18, verified). R37: U-gather software-pipelined across the 4-point
// loop. The hk LDS reuse serialized point pp+1's staging behind pp's fragment
// reads (lgkmcnt), exposing the 30-load gather latency each iteration. Now the
// gather lands in a 30-reg buffer (hval) with no LDS dependency: per iteration
// {convert+store hval -> LDS; issue pp+1's 30 global loads; MFMA(pp)} — the next
// gather flies under the MFMA+epilogue. Same arithmetic/order, bit-identical.
// (R38's deeper jv/av hoist REGRESSED 910->971: extra live ranges crossed an
// occupancy/spill threshold; the jv chain was already hidden. Reverted.)
template<bool WRITE_NEXT>
__global__ __launch_bounds__(256) void k_edge_agg(const void* __restrict__ W1,
    const void* __restrict__ b1, int colOff){
  __shared__ short hk_hi[4][32][64] __attribute__((aligned(16)));  // 16 KB
  __shared__ short hk_lo[4][32][64] __attribute__((aligned(16)));  // 16 KB
  const int tid = threadIdx.x;
  const int wid = tid >> 6, lane = tid & 63;
  const int ml = lane & 15, kgl = lane >> 4;
  short8 wh[2][4], wl[2][4];
  #pragma unroll
  for(int kt=0; kt<2; kt++)
    #pragma unroll
    for(int nt=0; nt<4; nt++)
      #pragma unroll
      for(int j=0; j<8; j++){
        float w = ldi(W1, (size_t)(kt*32 + kgl*8 + j)*64 + nt*16 + ml);
        short hi = f2bs(w);
        wh[kt][nt][j] = hi;
        wl[kt][nt][j] = f2bs(w - bs2f(hi));
      }
  const float bias = ldi(b1, lane);
  hk_hi[wid][30][lane] = 0; hk_hi[wid][31][lane] = 0;
  hk_lo[wid][30][lane] = 0; hk_lo[wid][31][lane] = 0;

  float hval[KNN];
  float av;
  // prologue: gather point (pp=0) into registers
  {
    const int point = blockIdx.x*16 + wid*4;
    const int b0_ = point >> 11;
    const int* ip = g_idx + (size_t)point*KNN;
    int jv = 0;
    if(lane < KNN) jv = ip[lane] & (NN-1);
    av = g_ws[A_O + (size_t)point*64 + lane];
    const float* Ub = g_ws + U_O + (size_t)b0_*NN*64;
    #pragma unroll
    for(int kk=0; kk<KNN; kk++){
      int j = __shfl(jv, kk, 64);
      hval[kk] = Ub[(size_t)j*64 + lane];
    }
  }

  for(int pp=0; pp<4; pp++){
    const int point = blockIdx.x*16 + wid*4 + pp;
    const int b = point >> 11, i = point & (NN-1);
    const float a = av;
    // convert + store current point's h into LDS (reads hval; frees it for prefetch)
    #pragma unroll
    for(int kk=0; kk<KNN; kk++){
      float h = fmaxf(a + hval[kk], 0.f);
      short hi = f2bs(h);
      hk_hi[wid][kk][lane] = hi;
      hk_lo[wid][kk][lane] = f2bs(h - bs2f(hi));
    }
    // prefetch next point's gather into hval (overlaps the MFMA below)
    if(pp < 3){
      const int np = point + 1;
      const int nb = np >> 11;
      const int* ip = g_idx + (size_t)np*KNN;
      int njv = 0;
      if(lane < KNN) njv = ip[lane] & (NN-1);
      av = g_ws[A_O + (size_t)np*64 + lane];
      const float* Ub = g_ws + U_O + (size_t)nb*NN*64;
      #pragma unroll
      for(int kk=0; kk<KNN; kk++){
        int j = __shfl(njv, kk, 64);
        hval[kk] = Ub[(size_t)j*64 + lane];
      }
    }
    floatx4 acc[2][4];
    #pragma unroll
    for(int t=0;t<2;t++)
      #pragma unroll
      for(int nt=0;nt<4;nt++) acc[t][nt] = (floatx4){0.f,0.f,0.f,0.f};
    #pragma unroll
    for(int t=0;t<2;t++){
      #pragma unroll
      for(int kt=0;kt<2;kt++){
        short8 ah = *(const short8*)&hk_hi[wid][t*16+ml][kt*32 + kgl*8];
        short8 al = *(const short8*)&hk_lo[wid][t*16+ml][kt*32 + kgl*8];
        #pragma unroll
        for(int nt=0;nt<4;nt++){
          acc[t][nt] = __builtin_amdgcn_mfma_f32_16x16x32_bf16(ah, wh[kt][nt], acc[t][nt], 0,0,0);
          acc[t][nt] = __builtin_amdgcn_mfma_f32_16x16x32_bf16(ah, wl[kt][nt], acc[t][nt], 0,0,0);
          acc[t][nt] = __builtin_amdgcn_mfma_f32_16x16x32_bf16(al, wh[kt][nt], acc[t][nt], 0,0,0);
        }
      }
    }
    float cmax[4];
    #pragma unroll
    for(int nt=0;nt<4;nt++){
      float mx = -FLT_MAX;
      #pragma unroll
      for(int t=0;t<2;t++)
        #pragma unroll
        for(int reg=0;reg<4;reg++){
          int m = t*16 + kgl*4 + reg;
          if(m < KNN) mx = fmaxf(mx, acc[t][nt][reg]);
        }
      mx = fmaxf(mx, __shfl_xor(mx, 16, 64));
      mx = fmaxf(mx, __shfl_xor(mx, 32, 64));
      cmax[nt] = mx;
    }
    float r01 = (lane & 16) ? cmax[1] : cmax[0];
    float r23 = (lane & 16) ? cmax[3] : cmax[2];
    float accf = ((lane & 32) ? r23 : r01) + bias;
    g_ws[H_O + (size_t)point*192 + colOff + lane] = accf;
    if(WRITE_NEXT){
      g_ws[XT_O + ((size_t)b*64 + lane)*NN + i] = accf; // transposed copy for next kNN
      float sq = accf*accf;
      #pragma unroll
      for(int off=32; off>0; off>>=1) sq += __shfl_xor(sq, off, 64);
      if(lane == 0) g_ws[NRM_O + point] = sq;
    }
  }
}

// ---------------------------------------------------------------- weight preconvert (all 3): fp32 [K][N] -> fragment-major bf16
__global__ __launch_bounds__(256) void k_wconv3(const void* __restrict__ W0,
    const void* __restrict__ W1, const void* __restrict__ W2){
  int t = blockIdx.x*256 + threadIdx.x;            // grid=1920 -> t < 491520 exactly
  const void* W; int dstOff, rel, lg;
  if(t < 196608)      { W = W0; dstOff = (int)WB1_S; rel = t;          lg = 10; }
  else if(t < 458752) { W = W1; dstOff = (int)WB2_S; rel = t - 196608; lg = 8;  }
  else                { W = W2; dstOff = (int)WB3_S; rel = t - 458752; lg = 7;  }
  int k = rel >> lg, n = rel & ((1<<lg)-1);
  short* dst = (short*)g_ws + dstOff;
  dst[((size_t)((k>>3) << lg) + ((size_t)n))*8 + (k&7)] = f2bs(ldi(W, rel));
}

// ---------------------------------------------------------------- MFMA GEMM: Out = act(A @ W + bias)
// Block 256 = 2x2 waves, tile 128x128, wave 64x64, K-step 32, mfma_f32_16x16x32_bf16.
template<bool ABF16, bool RELU, bool OUTBF16>
__global__ __launch_bounds__(256) void k_mgemm(int aOff, int wOffS, const void* __restrict__ bias,
    int outOff, int Kd, int Nn){
  __shared__ short As[4*128*8] __attribute__((aligned(16)));   // [kg][m][j] 8 KB
  __shared__ short Bs[4*128*8] __attribute__((aligned(16)));   // [kg][n][j] 8 KB
  const int tid = threadIdx.x;
  const int lane = tid & 63, wid = tid >> 6;
  const int waveM = wid >> 1, waveN = wid & 1;
  const int m0 = blockIdx.x * 128, n0 = blockIdx.y * 128;
  const int sm = tid >> 1, skg0 = (tid & 1) * 2;     // A-stage: row sm, k-groups skg0,skg0+1
  const int bn = tid & 127, bkg = tid >> 7;          // B-stage: n, k-groups bkg, bkg+2
  const short* Wb = (const short*)g_ws + wOffS;
  floatx4 acc[4][4];
  #pragma unroll
  for(int a=0;a<4;a++)
    #pragma unroll
    for(int bq=0;bq<4;bq++) acc[a][bq] = (floatx4){0.f,0.f,0.f,0.f};

  for(int k0 = 0; k0 < Kd; k0 += 32){
    if(ABF16){
      const short* Ab = (const short*)g_ws + aOff + (size_t)(m0+sm)*Kd + k0 + skg0*8;
      short8 v0 = *(const short8*)Ab;
      short8 v1 = *(const short8*)(Ab+8);
      *(short8*)&As[((skg0  )*128 + sm)*8] = v0;
      *(short8*)&As[((skg0+1)*128 + sm)*8] = v1;
    } else {
      const float* Af = g_ws + aOff + (size_t)(m0+sm)*Kd + k0 + skg0*8;
      float4 f0 = *(const float4*)(Af+0);
      float4 f1 = *(const float4*)(Af+4);
      float4 f2 = *(const float4*)(Af+8);
      float4 f3 = *(const float4*)(Af+12);
      short8 s0, s1;
      s0[0]=f2bs(f0.x); s0[1]=f2bs(f0.y); s0[2]=f2bs(f0.z); s0[3]=f2bs(f0.w);
      s0[4]=f2bs(f1.x); s0[5]=f2bs(f1.y); s0[6]=f2bs(f1.z); s0[7]=f2bs(f1.w);
      s1[0]=f2bs(f2.x); s1[1]=f2bs(f2.y); s1[2]=f2bs(f2.z); s1[3]=f2bs(f2.w);
      s1[4]=f2bs(f3.x); s1[5]=f2bs(f3.y); s1[6]=f2bs(f3.z); s1[7]=f2bs(f3.w);
      *(short8*)&As[((skg0  )*128 + sm)*8] = s0;
      *(short8*)&As[((skg0+1)*128 + sm)*8] = s1;
    }
    #pragma unroll
    for(int i=0;i<2;i++){
      int kg = bkg + i*2;
      const short* src = Wb + ((size_t)((k0>>3) + kg)*Nn + n0 + bn)*8;
      *(short8*)&Bs[(kg*128 + bn)*8] = *(const short8*)src;
    }
    __syncthreads();
    const int kgl = lane >> 4, ml = lane & 15;
    short8 af[4], bf[4];
    #pragma unroll
    for(int t=0;t<4;t++){
      af[t] = *(const short8*)&As[(kgl*128 + waveM*64 + t*16 + ml)*8];
      bf[t] = *(const short8*)&Bs[(kgl*128 + waveN*64 + t*16 + ml)*8];
    }
    #pragma unroll
    for(int tm=0;tm<4;tm++)
      #pragma unroll
      for(int tn=0;tn<4;tn++)
        acc[tm][tn] = __builtin_amdgcn_mfma_f32_16x16x32_bf16(af[tm], bf[tn], acc[tm][tn], 0, 0, 0);
    __syncthreads();
  }
  // epilogue: D col=lane&15, row=(lane>>4)*4+reg  [m89]
  const int kgl = lane >> 4, ml = lane & 15;
  #pragma unroll
  for(int tn=0;tn<4;tn++){
    int n = n0 + waveN*64 + tn*16 + ml;
    float bv = ldi(bias, n);
    #pragma unroll
    for(int tm=0;tm<4;tm++){
      #pragma unroll
      for(int reg=0;reg<4;reg++){
        int m = m0 + waveM*64 + tm*16 + kgl*4 + reg;
        float v = acc[tm][tn][reg] + bv;
        if(RELU) v = fmaxf(v, 0.f);
        if(OUTBF16) ((short*)g_ws)[(size_t)outOff + (size_t)m*Nn + n] = f2bs(v);
        else        g_ws[(size_t)outOff + (size_t)m*Nn + n] = v;
      }
    }
  }
}

// ---------------------------------------------------------------- fused w2-GEMM (256->128, no relu) + final 128->3
// Tile m=128 x n=128(full). h3 kept fp32 in LDS (one less bf16 rounding than old k_final path).
__global__ __launch_bounds__(256) void k_mgemm_fin(int aOff, int wOffS,
    const void* __restrict__ bias, const void* __restrict__ FW, const void* __restrict__ FB,
    void* __restrict__ out, int outPointBase){
  __shared__ short As[4*128*8] __attribute__((aligned(16)));   // 8 KB
  __shared__ short Bs[4*128*8] __attribute__((aligned(16)));   // 8 KB
  __shared__ float h3[128][129];                               // 66 KB (pad: conflict-free col reads)
  __shared__ float wf[384];
  __shared__ float fb3[3];
  const int Kd = 256, Nn = 128;
  const int tid = threadIdx.x;
  const int lane = tid & 63, wid = tid >> 6;
  const int waveM = wid >> 1, waveN = wid & 1;
  const int m0 = blockIdx.x * 128;
  const int sm = tid >> 1, skg0 = (tid & 1) * 2;
  const int bn = tid & 127, bkg = tid >> 7;
  const short* Wb = (const short*)g_ws + wOffS;
  for(int t=tid; t<384; t+=256) wf[t] = ldi(FW, t);
  if(tid < 3) fb3[tid] = ldi(FB, tid);
  floatx4 acc[4][4];
  #pragma unroll
  for(int a=0;a<4;a++)
    #pragma unroll
    for(int bq=0;bq<4;bq++) acc[a][bq] = (floatx4){0.f,0.f,0.f,0.f};

  for(int k0 = 0; k0 < Kd; k0 += 32){
    const short* Ab = (const short*)g_ws + aOff + (size_t)(m0+sm)*Kd + k0 + skg0*8;
    short8 v0 = *(const short8*)Ab;
    short8 v1 = *(const short8*)(Ab+8);
    *(short8*)&As[((skg0  )*128 + sm)*8] = v0;
    *(short8*)&As[((skg0+1)*128 + sm)*8] = v1;
    #pragma unroll
    for(int i=0;i<2;i++){
      int kg = bkg + i*2;
      const short* src = Wb + ((size_t)((k0>>3) + kg)*Nn + bn)*8;
      *(short8*)&Bs[(kg*128 + bn)*8] = *(const short8*)src;
    }
    __syncthreads();
    const int kgl = lane >> 4, ml = lane & 15;
    short8 af[4], bf[4];
    #pragma unroll
    for(int t=0;t<4;t++){
      af[t] = *(const short8*)&As[(kgl*128 + waveM*64 + t*16 + ml)*8];
      bf[t] = *(const short8*)&Bs[(kgl*128 + waveN*64 + t*16 + ml)*8];
    }
    #pragma unroll
    for(int tm=0;tm<4;tm++)
      #pragma unroll
      for(int tn=0;tn<4;tn++)
        acc[tm][tn] = __builtin_amdgcn_mfma_f32_16x16x32_bf16(af[tm], bf[tn], acc[tm][tn], 0, 0, 0);
    __syncthreads();
  }
  const int kgl = lane >> 4, ml = lane & 15;
  #pragma unroll
  for(int tn=0;tn<4;tn++){
    int n = waveN*64 + tn*16 + ml;
    float bv = ldi(bias, n);
    #pragma unroll
    for(int tm=0;tm<4;tm++){
      #pragma unroll
      for(int reg=0;reg<4;reg++){
        int m = waveM*64 + tm*16 + kgl*4 + reg;
        h3[m][n] = acc[tm][tn][reg] + bv;
      }
    }
  }
  __syncthreads();
  if(tid < 128){
    float a0 = fb3[0], a1 = fb3[1], a2 = fb3[2];
    #pragma unroll 8
    for(int c=0;c<128;c++){
      float x = h3[tid][c];
      a0 = fmaf(x, wf[c*3+0], a0);
      a1 = fmaf(x, wf[c*3+1], a1);
      a2 = fmaf(x, wf[c*3+2], a2);
    }
    size_t o = (size_t)(outPointBase + blockIdx.x*128 + tid)*3;
    if(g_isbf16){
      bf16* ob = (bf16*)out;
      ob[o+0] = __float2bfloat16(a0); ob[o+1] = __float2bfloat16(a1); ob[o+2] = __float2bfloat16(a2);
    } else {
      float* of = (float*)out;
      of[o+0] = a0; of[o+1] = a1; of[o+2] = a2;
    }
  }
}

extern "C" void kernel_launch(void* const* d_in, const int* in_sizes, int n_in,
                              void* d_out, int out_size, void* d_ws, size_t ws_size,
                              hipStream_t stream){
  (void)d_ws; (void)ws_size;
  static const int EXP[21] = {98304, 384,64, 4096,64, 8192,64, 4096,64, 8192,64, 4096,64,
                              196608,1024, 262144,256, 32768,128, 384,3};
  const void* in[21];
  int posmatch = 0;
  bool run = false;
  if(n_in == 21){
    for(int e=0; e<21; e++) posmatch += (in_sizes[e] == EXP[e]) ? 1 : 0;
    if(posmatch == 21){
      for(int e=0; e<21; e++) in[e] = d_in[e];
      run = true;
    } else {
      bool used[21] = {false}; const void* m[21]; bool ok = true;
      for(int e=0; e<21 && ok; e++){
        int hit = -1;
        for(int i2=0; i2<21; i2++)
          if(!used[i2] && in_sizes[i2] == EXP[e]){ hit = i2; break; }
        if(hit < 0) ok = false;
        else { used[hit] = true; m[e] = d_in[hit]; }
      }
      if(ok){ for(int e=0; e<21; e++) in[e] = m[e]; run = true; }
    }
  }
  if(!run){
    float V = 1000.f*(float)n_in + 10.f*(float)posmatch;
    k_diag<<<(out_size+255)/256, 256, 0, stream>>>((bf16*)d_out, out_size, V);
    return;
  }
  const void* pos  = in[0];
  const void* c1w0 = in[1];  const void* c1b0 = in[2];
  const void* c1w1 = in[3];  const void* c1b1 = in[4];
  const void* c2w0 = in[5];  const void* c2b0 = in[6];
  const void* c2w1 = in[7];  const void* c2b1 = in[8];
  const void* c3w0 = in[9];  const void* c3b0 = in[10];
  const void* c3w1 = in[11]; const void* c3b1 = in[12];
  const void* mw0  = in[13]; const void* mb0  = in[14];
  const void* mw1  = in[15]; const void* mb1  = in[16];
  const void* mw2  = in[17]; const void* mb2  = in[18];
  const void* fw   = in[19]; const void* fb   = in[20];

  dim3 b256(256);
  dim3 b512(512);
  k_prep<<<128, b256, 0, stream>>>(pos);           // R36: sniff folded in

  // stage 1 (C=3): fat = knn (blocks 0..4095) + stage_pre (blocks 4096..6143)
  k_knn_pre<3,true><<<6144, b512, 0, stream>>>(pos, 3, 0, c1w0, c1b0, 0);
  k_edge_agg<true><<<2048, b256, 0, stream>>>(c1w1, c1b1, 0);

  // stage 2 (C=64): x1 transposed in XT (stage-1 edge_agg); xi from H cols 0..63
  k_knn_pre<64,false><<<6144, b512, 0, stream>>>(nullptr, 192, 0, c2w0, c2b0, (int)H_O);
  k_edge_agg<true><<<2048, b256, 0, stream>>>(c2w1, c2b1, 64);

  // stage 3 (C=64): x2 transposed in XT; xi from H cols 64..127
  k_knn_pre<64,false><<<6144, b512, 0, stream>>>(nullptr, 192, 64, c3w0, c3b0, (int)H_O);
  k_edge_agg<false><<<2048, b256, 0, stream>>>(c3w1, c3b1, 128);

  // weight preconvert AFTER stage 3 (targets alias U-region, dead from here on)
  k_wconv3<<<1920, b256, 0, stream>>>(mw0, mw1, mw2);

  // final MLP: MFMA bf16, chunked M=8192; w2-GEMM + 128->3 fused (no H3 round-trip)
  for(int ch=0; ch<4; ch++){
    int ainOff = (int)(H_O + (size_t)ch*MC*192);
    k_mgemm<false,true ,true ><<<dim3(64,8), b256, 0, stream>>>(ainOff,     (int)WB1_S, mb0, (int)H1C_S, 192, 1024);
    k_mgemm<true ,true ,true ><<<dim3(64,2), b256, 0, stream>>>((int)H1C_S, (int)WB2_S, mb1, (int)H2C_S, 1024, 256);
    k_mgemm_fin<<<64, b256, 0, stream>>>((int)H2C_S, (int)WB3_S, mb2, fw, fb, d_out, ch*MC);
  }
}